// Round 1
// baseline (229.617 us; speedup 1.0000x reference)
//
#include <hip/hip_runtime.h>

#define ETA_MIN 0.6931471805599453f
#define ETA_MAX 10.0f

// Native vector type — __builtin_nontemporal_* rejects HIP_vector_type structs
// but accepts ext_vector_type. Lowers to global_{load,store}_dwordx4 nt.
typedef float vfloat4 __attribute__((ext_vector_type(4)));

__device__ __forceinline__ vfloat4 wcalc(vfloat4 l, float eta, float inv) {
    vfloat4 w;
    w.x = (l.x > eta) ? 0.0f : fmaf(-l.x, inv, 1.0f);
    w.y = (l.y > eta) ? 0.0f : fmaf(-l.y, inv, 1.0f);
    w.z = (l.z > eta) ? 0.0f : fmaf(-l.z, inv, 1.0f);
    w.w = (l.w > eta) ? 0.0f : fmaf(-l.w, inv, 1.0f);
    return w;
}

// Streaming elementwise: w_i = (loss_i > eta) ? 0 : 1 - loss_i/eta,
// eta = clamp(eta_value[0], log(2), 10).
//
// 268 MB total traffic (>> 32 MB L2), zero reuse -> non-temporal on both
// streams. Persistent grid-stride with a 4-deep unroll: each wave keeps
// 4 independent 16B loads in flight (vs 1 in the one-shot version) and
// the workgroup count drops 32768 -> 2048 (8 blocks/CU, full occupancy).
__global__ void __launch_bounds__(256) weights_kernel(
    const float* __restrict__ loss,
    const float* __restrict__ eta_value,
    float* __restrict__ out,
    int n4,          // number of float4 elements
    int tail_start,  // n4*4
    int n)           // total elements
{
    // Uniform load — scalar path, negligible.
    float eta = eta_value[0];
    eta = fminf(fmaxf(eta, ETA_MIN), ETA_MAX);
    const float inv = 1.0f / eta;

    const int tid    = blockIdx.x * blockDim.x + threadIdx.x;
    const int stride = gridDim.x * blockDim.x;   // total threads

    const vfloat4* __restrict__ in4  = reinterpret_cast<const vfloat4*>(loss);
    vfloat4*       __restrict__ out4 = reinterpret_cast<vfloat4*>(out);

    int i = tid;
    // Main loop: 4 independent nt-loads issued back-to-back, then 4 stores.
    // (n4 = 2^23 here, so with 2048x256 threads this runs exactly 4 times,
    //  16 float4 per thread total. Index math stays well inside int range.)
    for (; i + 3 * stride < n4; i += 4 * stride) {
        const vfloat4 l0 = __builtin_nontemporal_load(in4 + i);
        const vfloat4 l1 = __builtin_nontemporal_load(in4 + i + stride);
        const vfloat4 l2 = __builtin_nontemporal_load(in4 + i + 2 * stride);
        const vfloat4 l3 = __builtin_nontemporal_load(in4 + i + 3 * stride);
        const vfloat4 w0 = wcalc(l0, eta, inv);
        const vfloat4 w1 = wcalc(l1, eta, inv);
        const vfloat4 w2 = wcalc(l2, eta, inv);
        const vfloat4 w3 = wcalc(l3, eta, inv);
        __builtin_nontemporal_store(w0, out4 + i);
        __builtin_nontemporal_store(w1, out4 + i + stride);
        __builtin_nontemporal_store(w2, out4 + i + 2 * stride);
        __builtin_nontemporal_store(w3, out4 + i + 3 * stride);
    }
    // Remainder float4s (dead when n4 % (4*stride) == 0).
    for (; i < n4; i += stride) {
        __builtin_nontemporal_store(wcalc(__builtin_nontemporal_load(in4 + i), eta, inv),
                                    out4 + i);
    }

    // Scalar tail (n not divisible by 4). Dead for N=2^25.
    for (int t = tail_start + tid; t < n; t += stride) {
        const float l = loss[t];
        out[t] = (l > eta) ? 0.0f : fmaf(-l, inv, 1.0f);
    }
}

extern "C" void kernel_launch(void* const* d_in, const int* in_sizes, int n_in,
                              void* d_out, int out_size, void* d_ws, size_t ws_size,
                              hipStream_t stream) {
    const float* loss = (const float*)d_in[0];
    const float* eta  = (const float*)d_in[1];
    float* out        = (float*)d_out;
    const int n  = in_sizes[0];
    const int n4 = n / 4;
    const int tail_start = n4 * 4;

    const int block = 256;
    // Persistent-ish grid: 8 blocks/CU x 256 CUs = 2048 (32 waves/CU).
    // Cap by actual work so tiny n still launches correctly.
    int work = n4 > (n - tail_start) ? n4 : (n - tail_start);
    if (work < 1) work = 1;
    int grid = (work + block - 1) / block;
    if (grid > 2048) grid = 2048;

    weights_kernel<<<grid, block, 0, stream>>>(loss, eta, out, n4, tail_start, n);
}

// Round 2
// 222.574 us; speedup vs baseline: 1.0316x; 1.0316x over previous
//
#include <hip/hip_runtime.h>

#define ETA_MIN 0.6931471805599453f
#define ETA_MAX 10.0f

// Native vector type — __builtin_nontemporal_* rejects HIP_vector_type structs
// but accepts ext_vector_type. Lowers to global_{load,store}_dwordx4 nt.
typedef float vfloat4 __attribute__((ext_vector_type(4)));

__device__ __forceinline__ vfloat4 wcalc(vfloat4 l, float eta, float inv) {
    vfloat4 w;
    w.x = (l.x > eta) ? 0.0f : fmaf(-l.x, inv, 1.0f);
    w.y = (l.y > eta) ? 0.0f : fmaf(-l.y, inv, 1.0f);
    w.z = (l.z > eta) ? 0.0f : fmaf(-l.z, inv, 1.0f);
    w.w = (l.w > eta) ? 0.0f : fmaf(-l.w, inv, 1.0f);
    return w;
}

// Streaming elementwise: w_i = (loss_i > eta) ? 0 : 1 - loss_i/eta,
// eta = clamp(eta_value[0], log(2), 10).
//
// One-shot (no grid-stride loop — R1 showed loop-carried register reuse
// between nt-stores and next-iteration loads serializes on vmcnt, −13 µs).
// Each thread handles TWO independent float4s at i and i+n4/2: straight-line
// body, distinct registers, so both loads are in flight before the first
// vmcnt wait. Wave retire/relaunch provides the rest of the pipelining.
__global__ void __launch_bounds__(256) weights_kernel(
    const float* __restrict__ loss,
    const float* __restrict__ eta_value,
    float* __restrict__ out,
    int n4_half,     // n4 / 2
    int n4,          // number of float4 elements
    int tail_start,  // n4*4
    int n)           // total elements
{
    // Uniform load — scalar path, negligible.
    float eta = eta_value[0];
    eta = fminf(fmaxf(eta, ETA_MIN), ETA_MAX);
    const float inv = 1.0f / eta;

    const int i = blockIdx.x * blockDim.x + threadIdx.x;

    const vfloat4* __restrict__ in4  = reinterpret_cast<const vfloat4*>(loss);
    vfloat4*       __restrict__ out4 = reinterpret_cast<vfloat4*>(out);

    if (i < n4_half) {
        // Two contiguous streams (lower half / upper half), both perfectly
        // coalesced per instruction; independent registers.
        const vfloat4 l0 = __builtin_nontemporal_load(in4 + i);
        const vfloat4 l1 = __builtin_nontemporal_load(in4 + i + n4_half);
        const vfloat4 w0 = wcalc(l0, eta, inv);
        const vfloat4 w1 = wcalc(l1, eta, inv);
        __builtin_nontemporal_store(w0, out4 + i);
        __builtin_nontemporal_store(w1, out4 + i + n4_half);
    }

    // Odd float4 in the middle (dead when n4 is even; n4 = 2^23 here).
    if ((n4 & 1) && i == 0) {
        const int m = n4 - 1;
        __builtin_nontemporal_store(
            wcalc(__builtin_nontemporal_load(in4 + m), eta, inv), out4 + m);
    }

    // Scalar tail (n not divisible by 4). Dead for N=2^25.
    const int t = tail_start + i;
    if (i < n - tail_start) {
        const float l = loss[t];
        out[t] = (l > eta) ? 0.0f : fmaf(-l, inv, 1.0f);
    }
}

extern "C" void kernel_launch(void* const* d_in, const int* in_sizes, int n_in,
                              void* d_out, int out_size, void* d_ws, size_t ws_size,
                              hipStream_t stream) {
    const float* loss = (const float*)d_in[0];
    const float* eta  = (const float*)d_in[1];
    float* out        = (float*)d_out;
    const int n  = in_sizes[0];
    const int n4 = n / 4;
    const int n4_half = n4 / 2;
    const int tail_start = n4 * 4;

    const int block = 256;
    int work = n4_half;
    if (n - tail_start > work) work = n - tail_start;
    if (work < 1) work = 1;
    const int grid = (work + block - 1) / block;

    weights_kernel<<<grid, block, 0, stream>>>(loss, eta, out, n4_half, n4,
                                               tail_start, n);
}